// Round 11
// baseline (102.219 us; speedup 1.0000x reference)
//
#include <hip/hip_runtime.h>
#include <stdint.h>

// B=4, L=128, D=256, NUM_KNOTS=64, HEAD_DIM=4 -> N = 8192 knots/batch, 512 rows.
#define NQ 8192
#define DIM 256
#define KSPLIT 8

// 0.5 (= 1/sqrt(4)) * log2(e): fold softmax scale + base-2 conversion into Q.
#define QSCALE 0.7213475204444817f

typedef _Float16 half8  __attribute__((ext_vector_type(8)));
typedef float    f32x16 __attribute__((ext_vector_type(16)));

union H8 { uint32_t u[4]; half8 h; };

__device__ __forceinline__ float ex2(float x) { return __builtin_amdgcn_exp2f(x); }
__device__ __forceinline__ uint32_t pkrtz(float a, float b) {
    auto h = __builtin_amdgcn_cvt_pkrtz(a, b);   // __fp16 ext_vector(2)
    return __builtin_bit_cast(uint32_t, h);
}

// ---------------------------------------------------------------------------
// QKV projection -> f16 buffers for the MFMA attention.
//   Qh[b][n][8]: comps 0-3 = f16(hi) of Q*QSCALE, 4-7 = f16 residual (lo)
//   Kh[b][n][8]: same for K
//   Vthi/Vtlo[b][c][n]: V transposed comp-major, f16 hi + f16 residual
// Grid (128 rowtiles, 3 matrices) x 256 thr; 4 rows/block.
// ---------------------------------------------------------------------------
__global__ __launch_bounds__(256) void qkv_proj(
    const float* __restrict__ x,
    const float* __restrict__ Wq, const float* __restrict__ Wk,
    const float* __restrict__ Wv,
    _Float16* __restrict__ Qh, _Float16* __restrict__ Kh,
    _Float16* __restrict__ Vthi, _Float16* __restrict__ Vtlo)
{
    const int m = blockIdx.y;
    const float* W = (m == 0) ? Wq : (m == 1) ? Wk : Wv;
    const int j  = threadIdx.x;
    const int rb = blockIdx.x * 4;

    float acc[4] = {0.f, 0.f, 0.f, 0.f};
    const float4* __restrict__ W4 = reinterpret_cast<const float4*>(W + j * DIM);
    const float*  __restrict__ A0 = x + rb * DIM;

    #pragma unroll 4
    for (int d4 = 0; d4 < DIM / 4; ++d4) {
        const float4 w = W4[d4];
        #pragma unroll
        for (int r = 0; r < 4; ++r) {
            const float4 a = reinterpret_cast<const float4*>(A0 + r * DIM)[d4];
            acc[r] = fmaf(a.x, w.x, acc[r]);
            acc[r] = fmaf(a.y, w.y, acc[r]);
            acc[r] = fmaf(a.z, w.z, acc[r]);
            acc[r] = fmaf(a.w, w.w, acc[r]);
        }
    }
    #pragma unroll
    for (int r = 0; r < 4; ++r) {
        const int rr = rb + r;
        const int bb = rr >> 7, rowin = rr & 127;
        const int n = rowin * 64 + (j >> 2), comp = j & 3;
        if (m == 2) {
            const _Float16 hi = (_Float16)acc[r];
            const _Float16 lo = (_Float16)(acc[r] - (float)hi);
            Vthi[((size_t)bb * 4 + comp) * NQ + n] = hi;
            Vtlo[((size_t)bb * 4 + comp) * NQ + n] = lo;
        } else {
            const float v = (m == 0) ? acc[r] * QSCALE : acc[r];
            const _Float16 hi = (_Float16)v;
            const _Float16 lo = (_Float16)(v - (float)hi);
            _Float16* dst = ((m == 0) ? Qh : Kh) + ((size_t)bb * NQ + n) * 8 + comp;
            dst[0] = hi;
            dst[4] = lo;
        }
    }
}

// ---------------------------------------------------------------------------
// MFMA attention. Grid (64 qquads, 8 ksplits, 4 batches) x 256 thr = 4 waves.
// Wave = one 32-query strip over a 1024-key range (32 tiles of 32 keys).
// S^T[key][q] = K_tile @ Q^T via 3 compensated mfma_32x32x16_f16; the spare
// K-dim comp 4 carries a constant bias: A comp4 = -10, B comp4 = 1 -> every
// S entry gets -10 for free, keeping p = exp2(S) within f16 range (overflow
// was R10's 5.5e-2 failure; q·k<=36 covered, subnormal tail <5e-5 relative,
// num/den ratio shift-invariant). P -> f16 via cvt_pkrtz; permlane32_swap
// reshapes C-layout into the PV B-frag layout. PV: 4 MFMAs (V hi + lo
// residual per 16-key half); V^T row 4 = ones (hi only) accumulates lsum.
// Partial (4 comps + lsum) -> Pp[b][ks][n][8]. No LDS, no barriers.
// ---------------------------------------------------------------------------
__global__ __launch_bounds__(256) void attn_mfma(
    const _Float16* __restrict__ Qh, const _Float16* __restrict__ Kh,
    const _Float16* __restrict__ Vthi, const _Float16* __restrict__ Vtlo,
    float* __restrict__ Pp)
{
    const int t    = threadIdx.x;
    const int w    = t >> 6;
    const int lane = t & 63;
    const int lo   = lane & 31, hi = lane >> 5;
    const int qstrip = blockIdx.x * 4 + w;   // 0..255
    const int ks     = blockIdx.y;           // 0..7
    const int b      = blockIdx.z;           // 0..3
    const int qbase  = qstrip * 32;
    const int kbase  = ks * 1024;

    // Q fragments (B-operand of S^T mfma), loop-invariant.
    // comp4 of qhi = 1.0 (bias row multiplier); lanes>=32 all zero.
    H8 qhi, qlo;
    {
        uint4 qd = make_uint4(0, 0, 0, 0);
        if (lane < 32)
            qd = *reinterpret_cast<const uint4*>(Qh + ((size_t)b * NQ + qbase + lo) * 8);
        qhi.u[0] = qd.x; qhi.u[1] = qd.y;
        qhi.u[2] = (lane < 32) ? 0x00003C00u : 0u;   // comp4 = 1.0 f16
        qhi.u[3] = 0;
        qlo.u[0] = qd.z; qlo.u[1] = qd.w; qlo.u[2] = 0; qlo.u[3] = 0;
    }
    const _Float16* __restrict__ KhB = Kh + (size_t)b * NQ * 8;
    const int c = lo;  // V^T component row for this lane
    const _Float16* __restrict__ VrowH = Vthi + ((size_t)b * 4 + (c < 4 ? c : 0)) * NQ;
    const _Float16* __restrict__ VrowL = Vtlo + ((size_t)b * 4 + (c < 4 ? c : 0)) * NQ;

    f32x16 acc = {};

    // K-tile load: lanes<32: 16B = {khi x4, klo x4} of key kt+lo.
    auto LDK = [&](int kt) -> uint4 {
        return (lane < 32)
            ? *reinterpret_cast<const uint4*>(KhB + (size_t)(kt + lo) * 8)
            : make_uint4(0, 0, 0, 0);
    };
    // V^T hi A-frag (keys kt + hi*8 .. +7 of comp c; row4 = ones for lsum):
    auto LDVH = [&](int kt) -> uint4 {
        if (c < 4)  return *reinterpret_cast<const uint4*>(VrowH + kt + hi * 8);
        if (c == 4) return make_uint4(0x3C003C00u, 0x3C003C00u, 0x3C003C00u, 0x3C003C00u);
        return make_uint4(0, 0, 0, 0);
    };
    // V^T lo-residual A-frag (row4 = 0 -> no double-counted lsum):
    auto LDVL = [&](int kt) -> uint4 {
        if (c < 4) return *reinterpret_cast<const uint4*>(VrowL + kt + hi * 8);
        return make_uint4(0, 0, 0, 0);
    };

    uint4 kd  = LDK(kbase);
    uint4 v1h = LDVH(kbase),      v1l = LDVL(kbase);
    uint4 v2h = LDVH(kbase + 16), v2l = LDVL(kbase + 16);

    #pragma unroll 1
    for (int tt = 0; tt < 32; ++tt) {
        uint4 kdn = kd, v1hn = v1h, v1ln = v1l, v2hn = v2h, v2ln = v2l;
        if (tt < 31) {
            const int kt2 = kbase + (tt + 1) * 32;
            kdn = LDK(kt2);
            v1hn = LDVH(kt2);      v1ln = LDVL(kt2);
            v2hn = LDVH(kt2 + 16); v2ln = LDVL(kt2 + 16);
        }

        H8 ahi, alo;
        ahi.u[0] = kd.x; ahi.u[1] = kd.y;
        ahi.u[2] = (lane < 32) ? 0x0000C900u : 0u;   // comp4 = -10.0 f16 bias
        ahi.u[3] = 0;
        alo.u[0] = kd.z; alo.u[1] = kd.w; alo.u[2] = 0; alo.u[3] = 0;
        f32x16 z = {};
        f32x16 S = __builtin_amdgcn_mfma_f32_32x32x16_f16(ahi.h, qhi.h, z, 0, 0, 0);
        S = __builtin_amdgcn_mfma_f32_32x32x16_f16(ahi.h, qlo.h, S, 0, 0, 0);
        S = __builtin_amdgcn_mfma_f32_32x32x16_f16(alo.h, qhi.h, S, 0, 0, 0);

        float p[16];
        #pragma unroll
        for (int g = 0; g < 16; ++g) p[g] = ex2(S[g]);

        // keys 0-15 of this tile
        uint32_t u0 = pkrtz(p[0], p[1]), u1 = pkrtz(p[2], p[3]);
        uint32_t u2 = pkrtz(p[4], p[5]), u3 = pkrtz(p[6], p[7]);
        asm("v_permlane32_swap_b32 %0, %1" : "+v"(u0), "+v"(u2));
        asm("v_permlane32_swap_b32 %0, %1" : "+v"(u1), "+v"(u3));
        H8 pf1; pf1.u[0] = u0; pf1.u[1] = u1; pf1.u[2] = u2; pf1.u[3] = u3;
        H8 vf;
        vf.u[0] = v1h.x; vf.u[1] = v1h.y; vf.u[2] = v1h.z; vf.u[3] = v1h.w;
        acc = __builtin_amdgcn_mfma_f32_32x32x16_f16(vf.h, pf1.h, acc, 0, 0, 0);
        vf.u[0] = v1l.x; vf.u[1] = v1l.y; vf.u[2] = v1l.z; vf.u[3] = v1l.w;
        acc = __builtin_amdgcn_mfma_f32_32x32x16_f16(vf.h, pf1.h, acc, 0, 0, 0);

        // keys 16-31
        uint32_t u4 = pkrtz(p[8], p[9]),   u5 = pkrtz(p[10], p[11]);
        uint32_t u6 = pkrtz(p[12], p[13]), u7 = pkrtz(p[14], p[15]);
        asm("v_permlane32_swap_b32 %0, %1" : "+v"(u4), "+v"(u6));
        asm("v_permlane32_swap_b32 %0, %1" : "+v"(u5), "+v"(u7));
        H8 pf2; pf2.u[0] = u4; pf2.u[1] = u5; pf2.u[2] = u6; pf2.u[3] = u7;
        vf.u[0] = v2h.x; vf.u[1] = v2h.y; vf.u[2] = v2h.z; vf.u[3] = v2h.w;
        acc = __builtin_amdgcn_mfma_f32_32x32x16_f16(vf.h, pf2.h, acc, 0, 0, 0);
        vf.u[0] = v2l.x; vf.u[1] = v2l.y; vf.u[2] = v2l.z; vf.u[3] = v2l.w;
        acc = __builtin_amdgcn_mfma_f32_32x32x16_f16(vf.h, pf2.h, acc, 0, 0, 0);

        kd = kdn; v1h = v1hn; v1l = v1ln; v2h = v2hn; v2l = v2ln;
    }

    // Partial write. C-layout: col q = lane&31; lanes<32 regs 0-3 = comps 0-3;
    // lanes>=32 reg 0 = comp 4 = lsum.
    float* __restrict__ Pb = Pp + (((size_t)(b * KSPLIT + ks)) * NQ + qbase) * 8;
    if (lane < 32) {
        *reinterpret_cast<float4*>(Pb + lo * 8) =
            make_float4(acc[0], acc[1], acc[2], acc[3]);
    } else {
        Pb[lo * 8 + 4] = acc[0];
    }
}

// ---------------------------------------------------------------------------
// Fused merge + output projection. Grid 128 blocks x 256 thr; block = 4 rows
// = 256 knots. Phase 1: sum 8 ksplit partials, divide by lsum, stash AO tile
// in LDS. Phase 2: out = AO @ Wo^T + bo (aoL reads are uniform -> broadcast).
// ---------------------------------------------------------------------------
__global__ __launch_bounds__(256) void merge_oproj(
    const float* __restrict__ Pp, const float* __restrict__ Wo,
    const float* __restrict__ bo, float* __restrict__ out)
{
    __shared__ float aoL[4][DIM];      // 4 KB

    const int rb = blockIdx.x * 4;     // first row (0..508)
    const int b  = rb >> 7;            // batch
    const int n0 = (rb & 127) * 64;    // first knot within batch
    const int t  = threadIdx.x;        // knot offset 0..255

    {
        const int n = n0 + t;
        float4 num = make_float4(0.f, 0.f, 0.f, 0.f);
        float den = 0.f;
        #pragma unroll
        for (int s = 0; s < KSPLIT; ++s) {
            const float* q = Pp + (((size_t)(b * KSPLIT + s)) * NQ + n) * 8;
            const float4 v4 = *reinterpret_cast<const float4*>(q);
            num.x += v4.x; num.y += v4.y; num.z += v4.z; num.w += v4.w;
            den += q[4];
        }
        const float inv = 1.0f / den;
        const int row = t >> 6;
        const int d0  = (t & 63) * 4;
        aoL[row][d0 + 0] = num.x * inv;
        aoL[row][d0 + 1] = num.y * inv;
        aoL[row][d0 + 2] = num.z * inv;
        aoL[row][d0 + 3] = num.w * inv;
    }
    __syncthreads();

    const int j = t;
    float acc[4] = {0.f, 0.f, 0.f, 0.f};
    const float4* __restrict__ W4 = reinterpret_cast<const float4*>(Wo + j * DIM);
    #pragma unroll 4
    for (int d4 = 0; d4 < DIM / 4; ++d4) {
        const float4 wv = W4[d4];
        #pragma unroll
        for (int r = 0; r < 4; ++r) {
            const float4 a = reinterpret_cast<const float4*>(&aoL[r][0])[d4];
            acc[r] = fmaf(a.x, wv.x, acc[r]);
            acc[r] = fmaf(a.y, wv.y, acc[r]);
            acc[r] = fmaf(a.z, wv.z, acc[r]);
            acc[r] = fmaf(a.w, wv.w, acc[r]);
        }
    }
    const float bias = bo[j];
    #pragma unroll
    for (int r = 0; r < 4; ++r)
        out[(rb + r) * DIM + j] = acc[r] + bias;
}

extern "C" void kernel_launch(void* const* d_in, const int* in_sizes, int n_in,
                              void* d_out, int out_size, void* d_ws, size_t ws_size,
                              hipStream_t stream) {
    const float* x  = (const float*)d_in[0];
    const float* Wq = (const float*)d_in[1];
    const float* Wk = (const float*)d_in[2];
    const float* Wv = (const float*)d_in[3];
    const float* Wo = (const float*)d_in[4];
    const float* bo = (const float*)d_in[5];
    float* out = (float*)d_out;

    // Workspace layout:
    _Float16* Qh   = (_Float16*)d_ws;             // 262144 halfs (512 KB)
    _Float16* Kh   = Qh + 4 * NQ * 8;             // 262144 halfs (512 KB)
    _Float16* Vthi = Kh + 4 * NQ * 8;             // 131072 halfs (256 KB)
    _Float16* Vtlo = Vthi + 4 * 4 * NQ;           // 131072 halfs (256 KB)
    float*    Pp   = (float*)(Vtlo + 4 * 4 * NQ); // 2,097,152 f32 (8 MB)
    // total ~9.5 MB

    qkv_proj<<<dim3(128, 3), 256, 0, stream>>>(x, Wq, Wk, Wv, Qh, Kh, Vthi, Vtlo);
    attn_mfma<<<dim3(64, KSPLIT, 4), 256, 0, stream>>>(Qh, Kh, Vthi, Vtlo, Pp);
    merge_oproj<<<128, 256, 0, stream>>>(Pp, Wo, bo, out);
}

// Round 12
// 100.046 us; speedup vs baseline: 1.0217x; 1.0217x over previous
//
#include <hip/hip_runtime.h>
#include <stdint.h>

// B=4, L=128, D=256, NUM_KNOTS=64, HEAD_DIM=4 -> N = 8192 knots/batch, 512 rows.
#define NQ 8192
#define DIM 256
#define KSPLIT 8

// 0.5 (= 1/sqrt(4)) * log2(e): fold softmax scale + base-2 conversion into Q.
#define QSCALE 0.7213475204444817f

typedef _Float16 half8  __attribute__((ext_vector_type(8)));
typedef float    f32x16 __attribute__((ext_vector_type(16)));

union H8 { uint32_t u[4]; uint4 u4; half8 h; };

__device__ __forceinline__ float ex2(float x) { return __builtin_amdgcn_exp2f(x); }
__device__ __forceinline__ uint32_t pkrtz(float a, float b) {
    auto h = __builtin_amdgcn_cvt_pkrtz(a, b);   // __fp16 ext_vector(2)
    return __builtin_bit_cast(uint32_t, h);
}

// ---------------------------------------------------------------------------
// QKV projection -> PRE-PACKED MFMA fragments (one compensated-product MFMA):
//  Qpack[b][half][n][8]: half0 = [qhi0-3, qlo0-3]      (B-frag k0-7, lanes<32)
//                        half1 = [qhi0-3, 1, 0,0,0]    (B-frag k8-15, lanes>=32)
//  Kpack[b][half][n][8]: half0 = [khi0-3, khi0-3]      (A-frag k0-7)
//                        half1 = [klo0-3, -10, 0,0,0]  (A-frag k8-15)
//  -> S = khi·qhi + khi·qlo + klo·qhi - 10 in ONE mfma_32x32x16_f16.
//  Vpack[b][row][n]: rows 0-3 = Vhi comps, 4-7 = Vlo residual, 8 = ones
//  (rows 9-31 never written; their MFMA output rows are never read).
// Grid (128 rowtiles, 3 matrices) x 256 thr; 4 rows/block.
// ---------------------------------------------------------------------------
__global__ __launch_bounds__(256) void qkv_proj(
    const float* __restrict__ x,
    const float* __restrict__ Wq, const float* __restrict__ Wk,
    const float* __restrict__ Wv,
    _Float16* __restrict__ Qpack, _Float16* __restrict__ Kpack,
    _Float16* __restrict__ Vpack)
{
    const int m = blockIdx.y;
    const float* W = (m == 0) ? Wq : (m == 1) ? Wk : Wv;
    const int j  = threadIdx.x;
    const int rb = blockIdx.x * 4;

    float acc[4] = {0.f, 0.f, 0.f, 0.f};
    const float4* __restrict__ W4 = reinterpret_cast<const float4*>(W + j * DIM);
    const float*  __restrict__ A0 = x + rb * DIM;

    #pragma unroll 4
    for (int d4 = 0; d4 < DIM / 4; ++d4) {
        const float4 w = W4[d4];
        #pragma unroll
        for (int r = 0; r < 4; ++r) {
            const float4 a = reinterpret_cast<const float4*>(A0 + r * DIM)[d4];
            acc[r] = fmaf(a.x, w.x, acc[r]);
            acc[r] = fmaf(a.y, w.y, acc[r]);
            acc[r] = fmaf(a.z, w.z, acc[r]);
            acc[r] = fmaf(a.w, w.w, acc[r]);
        }
    }
    #pragma unroll
    for (int r = 0; r < 4; ++r) {
        const int rr = rb + r;
        const int bb = rr >> 7, rowin = rr & 127;
        const int n = rowin * 64 + (j >> 2), comp = j & 3;
        if (m == 2) {
            const _Float16 hi = (_Float16)acc[r];
            const _Float16 lo = (_Float16)(acc[r] - (float)hi);
            Vpack[((size_t)bb * 32 + comp) * NQ + n]     = hi;
            Vpack[((size_t)bb * 32 + 4 + comp) * NQ + n] = lo;
            if (comp == 0)
                Vpack[((size_t)bb * 32 + 8) * NQ + n] = (_Float16)1.0f;
        } else {
            const float v = (m == 0) ? acc[r] * QSCALE : acc[r];
            const _Float16 hi = (_Float16)v;
            const _Float16 lo = (_Float16)(v - (float)hi);
            _Float16* pk = (m == 0) ? Qpack : Kpack;
            _Float16* d0 = pk + (((size_t)bb * 2 + 0) * NQ + n) * 8;
            _Float16* d1 = pk + (((size_t)bb * 2 + 1) * NQ + n) * 8;
            if (m == 0) {
                d0[comp] = hi; d0[4 + comp] = lo;
                d1[comp] = hi;
                d1[4 + comp] = (comp == 0) ? (_Float16)1.0f : (_Float16)0.0f;
            } else {
                d0[comp] = hi; d0[4 + comp] = hi;
                d1[comp] = lo;
                d1[4 + comp] = (comp == 0) ? (_Float16)(-10.0f) : (_Float16)0.0f;
            }
        }
    }
}

// ---------------------------------------------------------------------------
// MFMA attention. Grid (64 qquads, 8 ksplits, 4 batches) x 256 thr = 4 waves.
// Wave = 32-query strip x 1024 keys (32 tiles of 32 keys). Per tile:
//   1 S-MFMA  (fragments loaded straight from Kpack/Qpack, bias folded)
//   16 exp2, 8 cvt_pkrtz, 4 permlane32_swap (P C-layout -> B-frag layout)
//   2 PV-MFMA (A straight from Vpack; rows 0-3 hi, 4-7 lo, 8 lsum-ones)
// Epilogue: 4 permlane+add folds lo rows (lanes>=32) into hi (lanes<32);
// partial (4 comps + lsum) -> Pp[b][ks][n][8]. No LDS, no barriers.
// ---------------------------------------------------------------------------
__global__ __launch_bounds__(256) void attn_mfma(
    const _Float16* __restrict__ Qpack, const _Float16* __restrict__ Kpack,
    const _Float16* __restrict__ Vpack, float* __restrict__ Pp)
{
    const int t    = threadIdx.x;
    const int w    = t >> 6;
    const int lane = t & 63;
    const int l5   = lane & 31, h1 = lane >> 5;
    const int qstrip = blockIdx.x * 4 + w;   // 0..255
    const int ks     = blockIdx.y;           // 0..7
    const int b      = blockIdx.z;           // 0..3
    const int qbase  = qstrip * 32;
    const int kbase  = ks * 1024;

    // B-frag (Q), loop-invariant: one unconditional dwordx4.
    H8 qf;
    qf.u4 = *reinterpret_cast<const uint4*>(
        Qpack + (((size_t)b * 2 + h1) * NQ + qbase + l5) * 8);

    const _Float16* __restrict__ Kb_ = Kpack + ((size_t)b * 2 + h1) * NQ * 8;
    const _Float16* __restrict__ Vb_ = Vpack + ((size_t)b * 32 + l5) * NQ + h1 * 8;

    f32x16 acc = {};

    auto LDK = [&](int kt) -> uint4 {
        return *reinterpret_cast<const uint4*>(Kb_ + (size_t)(kt + l5) * 8);
    };
    auto LDV = [&](int kt) -> uint4 {   // 8 f16 keys of this lane's V row
        return *reinterpret_cast<const uint4*>(Vb_ + kt);
    };

    uint4 kd = LDK(kbase);
    uint4 v1 = LDV(kbase);
    uint4 v2 = LDV(kbase + 16);

    #pragma unroll 2
    for (int tt = 0; tt < 32; ++tt) {
        uint4 kdn = kd, v1n = v1, v2n = v2;
        if (tt < 31) {
            const int kt2 = kbase + (tt + 1) * 32;
            kdn = LDK(kt2); v1n = LDV(kt2); v2n = LDV(kt2 + 16);
        }

        H8 af; af.u4 = kd;
        f32x16 z = {};
        f32x16 S = __builtin_amdgcn_mfma_f32_32x32x16_f16(af.h, qf.h, z, 0, 0, 0);

        float p[16];
        #pragma unroll
        for (int g = 0; g < 16; ++g) p[g] = ex2(S[g]);

        // keys 0-15: C-layout -> B-frag layout
        uint32_t u0 = pkrtz(p[0], p[1]), u1 = pkrtz(p[2], p[3]);
        uint32_t u2 = pkrtz(p[4], p[5]), u3 = pkrtz(p[6], p[7]);
        asm("v_permlane32_swap_b32 %0, %1" : "+v"(u0), "+v"(u2));
        asm("v_permlane32_swap_b32 %0, %1" : "+v"(u1), "+v"(u3));
        H8 pf1; pf1.u[0] = u0; pf1.u[1] = u1; pf1.u[2] = u2; pf1.u[3] = u3;
        H8 vf1; vf1.u4 = v1;
        acc = __builtin_amdgcn_mfma_f32_32x32x16_f16(vf1.h, pf1.h, acc, 0, 0, 0);

        // keys 16-31
        uint32_t u4 = pkrtz(p[8], p[9]),   u5 = pkrtz(p[10], p[11]);
        uint32_t u6 = pkrtz(p[12], p[13]), u7 = pkrtz(p[14], p[15]);
        asm("v_permlane32_swap_b32 %0, %1" : "+v"(u4), "+v"(u6));
        asm("v_permlane32_swap_b32 %0, %1" : "+v"(u5), "+v"(u7));
        H8 pf2; pf2.u[0] = u4; pf2.u[1] = u5; pf2.u[2] = u6; pf2.u[3] = u7;
        H8 vf2; vf2.u4 = v2;
        acc = __builtin_amdgcn_mfma_f32_32x32x16_f16(vf2.h, pf2.h, acc, 0, 0, 0);

        kd = kdn; v1 = v1n; v2 = v2n;
    }

    // Fold lo rows (lanes>=32 regs 0-3 = rows 4-7) into hi (lanes<32 rows 0-3).
    float n0 = acc[0], n1 = acc[1], n2 = acc[2], n3 = acc[3];
    const float ls = acc[4];             // row 8 (ones) = lsum, lanes<32
    float t0 = 0.f, t1 = 0.f, t2 = 0.f, t3 = 0.f;
    asm("v_permlane32_swap_b32 %0, %1" : "+v"(n0), "+v"(t0));
    asm("v_permlane32_swap_b32 %0, %1" : "+v"(n1), "+v"(t1));
    asm("v_permlane32_swap_b32 %0, %1" : "+v"(n2), "+v"(t2));
    asm("v_permlane32_swap_b32 %0, %1" : "+v"(n3), "+v"(t3));
    n0 += t0; n1 += t1; n2 += t2; n3 += t3;

    float* __restrict__ Pb = Pp + (((size_t)(b * KSPLIT + ks)) * NQ + qbase) * 8;
    if (lane < 32) {
        *reinterpret_cast<float4*>(Pb + l5 * 8) = make_float4(n0, n1, n2, n3);
        Pb[l5 * 8 + 4] = ls;
    }
}

// ---------------------------------------------------------------------------
// Fused merge + output projection. Grid 128 blocks x 256 thr; block = 4 rows
// = 256 knots. Phase 1: sum 8 ksplit partials, divide by lsum, stash AO tile
// in LDS. Phase 2: out = AO @ Wo^T + bo (aoL reads are uniform -> broadcast).
// ---------------------------------------------------------------------------
__global__ __launch_bounds__(256) void merge_oproj(
    const float* __restrict__ Pp, const float* __restrict__ Wo,
    const float* __restrict__ bo, float* __restrict__ out)
{
    __shared__ float aoL[4][DIM];      // 4 KB

    const int rb = blockIdx.x * 4;     // first row (0..508)
    const int b  = rb >> 7;            // batch
    const int n0 = (rb & 127) * 64;    // first knot within batch
    const int t  = threadIdx.x;        // knot offset 0..255

    {
        const int n = n0 + t;
        float4 num = make_float4(0.f, 0.f, 0.f, 0.f);
        float den = 0.f;
        #pragma unroll
        for (int s = 0; s < KSPLIT; ++s) {
            const float* q = Pp + (((size_t)(b * KSPLIT + s)) * NQ + n) * 8;
            const float4 v4 = *reinterpret_cast<const float4*>(q);
            num.x += v4.x; num.y += v4.y; num.z += v4.z; num.w += v4.w;
            den += q[4];
        }
        const float inv = 1.0f / den;
        const int row = t >> 6;
        const int d0  = (t & 63) * 4;
        aoL[row][d0 + 0] = num.x * inv;
        aoL[row][d0 + 1] = num.y * inv;
        aoL[row][d0 + 2] = num.z * inv;
        aoL[row][d0 + 3] = num.w * inv;
    }
    __syncthreads();

    const int j = t;
    float acc[4] = {0.f, 0.f, 0.f, 0.f};
    const float4* __restrict__ W4 = reinterpret_cast<const float4*>(Wo + j * DIM);
    #pragma unroll 4
    for (int d4 = 0; d4 < DIM / 4; ++d4) {
        const float4 wv = W4[d4];
        #pragma unroll
        for (int r = 0; r < 4; ++r) {
            const float4 a = reinterpret_cast<const float4*>(&aoL[r][0])[d4];
            acc[r] = fmaf(a.x, wv.x, acc[r]);
            acc[r] = fmaf(a.y, wv.y, acc[r]);
            acc[r] = fmaf(a.z, wv.z, acc[r]);
            acc[r] = fmaf(a.w, wv.w, acc[r]);
        }
    }
    const float bias = bo[j];
    #pragma unroll
    for (int r = 0; r < 4; ++r)
        out[(rb + r) * DIM + j] = acc[r] + bias;
}

extern "C" void kernel_launch(void* const* d_in, const int* in_sizes, int n_in,
                              void* d_out, int out_size, void* d_ws, size_t ws_size,
                              hipStream_t stream) {
    const float* x  = (const float*)d_in[0];
    const float* Wq = (const float*)d_in[1];
    const float* Wk = (const float*)d_in[2];
    const float* Wv = (const float*)d_in[3];
    const float* Wo = (const float*)d_in[4];
    const float* bo = (const float*)d_in[5];
    float* out = (float*)d_out;

    // Workspace layout:
    _Float16* Qpack = (_Float16*)d_ws;               // 4*2*8192*8 = 524288 h (1 MB)
    _Float16* Kpack = Qpack + 4 * 2 * NQ * 8;        // 524288 h (1 MB)
    _Float16* Vpack = Kpack + 4 * 2 * NQ * 8;        // 4*32*8192 = 1048576 h (2 MB)
    float*    Pp    = (float*)(Vpack + 4 * 32 * NQ); // 4*8*8192*8 = 2097152 f32 (8 MB)
    // total = 12 MB

    qkv_proj<<<dim3(128, 3), 256, 0, stream>>>(x, Wq, Wk, Wv, Qpack, Kpack, Vpack);
    attn_mfma<<<dim3(64, KSPLIT, 4), 256, 0, stream>>>(Qpack, Kpack, Vpack, Pp);
    merge_oproj<<<128, 256, 0, stream>>>(Pp, Wo, bo, out);
}